// Round 5
// baseline (40.266 us; speedup 1.0000x reference)
//
#include <hip/hip_runtime.h>

#define MM 48
#define BMOL 128
#define CUTOFF_V 1.5f
#define PI_F 3.14159265358979f

typedef float v4f __attribute__((ext_vector_type(4)));

// acos via A&S 4.4.45 (max err 6.7e-5); equals atan2(sqrt(n2i*n2k - a*a), a)
// for unit-normalized cosine x = a * rsqrt(n2i) * rsqrt(n2k).
__device__ __forceinline__ float acos_poly(float x) {
    x = fminf(fmaxf(x, -1.0f), 1.0f);
    float s = fabsf(x);
    float p = sqrtf(1.0f - s) *
              (1.5707288f + s * (-0.2121144f + s * (0.074261f - 0.0187293f * s)));
    return (x >= 0.0f) ? p : (PI_F - p);
}

// Flat, barrier-free, LDS-free: thread-iter owns one float4 quad of
// angles[b][j][i][k0..k0+3]. Coords (72 KB) live in L1/L2; everything is
// recomputed per thread. 8 quads per thread amortize wave overhead and give
// 8 independent in-flight nt stores per lane.
#define ANG_BLOCKS 1728
#define ANG_ITERS  8
__global__ __launch_bounds__(256)
void angles_kernel(const float* __restrict__ coords,
                   float* __restrict__ angles)
{
    const int tid = blockIdx.x * 256 + threadIdx.x;
    const int nthreads = ANG_BLOCKS * 256;   // 442368; *8 = 3,538,944 quads exact

#pragma unroll
    for (int it = 0; it < ANG_ITERS; ++it) {
        int q = tid + it * nthreads;
        int q12 = q / 12;
        int k0  = (q - q12 * 12) * 4;        // 0,4,...,44
        int i   = q12 % 48;
        int t2  = q12 / 48;
        int j   = t2 % 48;
        int b   = t2 / 48;

        const float* cb = coords + (size_t)b * (MM * 3);
        float jx = cb[j * 3], jy = cb[j * 3 + 1], jz = cb[j * 3 + 2];
        float ix = cb[i * 3], iy = cb[i * 3 + 1], iz = cb[i * 3 + 2];
        // 12 consecutive floats = coords of atoms k0..k0+3 (48B-aligned)
        v4f c0 = *(const v4f*)(cb + k0 * 3);
        v4f c1 = *(const v4f*)(cb + k0 * 3 + 4);
        v4f c2 = *(const v4f*)(cb + k0 * 3 + 8);
        float kc[12] = {c0.x, c0.y, c0.z, c0.w, c1.x, c1.y, c1.z, c1.w,
                        c2.x, c2.y, c2.z, c2.w};

        float vix = ix - jx, viy = iy - jy, viz = iz - jz;
        float n2i = vix * vix + viy * viy + viz * viz;
        bool adji = (i != j) && (sqrtf(n2i) < CUTOFF_V);
        float wi  = adji ? rsqrtf(n2i) : 0.0f;

        float ang[4];
#pragma unroll
        for (int e = 0; e < 4; ++e) {
            float vkx = kc[3 * e]     - jx;
            float vky = kc[3 * e + 1] - jy;
            float vkz = kc[3 * e + 2] - jz;
            float n2k = vkx * vkx + vky * vky + vkz * vkz;
            int   k   = k0 + e;
            bool adjk = (k != j) && (sqrtf(n2k) < CUTOFF_V);
            float wk  = adjk ? rsqrtf(n2k) : 0.0f;
            float a   = vix * vkx + viy * vky + viz * vkz;
            float w   = wi * wk;                  // >0 iff both edges adjacent
            float r   = acos_poly(a * w);
            bool mask = (w > 0.0f) && (i != k);
            ang[e] = mask ? r : 0.0f;
        }

        v4f res = {ang[0], ang[1], ang[2], ang[3]};
        __builtin_nontemporal_store(res, (v4f*)(angles + (size_t)q * 4));
    }
}

// dists[b][j][k]: 73728 quads, one per thread, 288 blocks.
__global__ __launch_bounds__(256)
void dists_kernel(const float* __restrict__ coords,
                  float* __restrict__ dists)
{
    const int q = blockIdx.x * 256 + threadIdx.x;   // 0..73727
    int rem = q % 576;
    int b   = q / 576;
    int j   = rem / 12;
    int k0  = (rem - j * 12) * 4;

    const float* cb = coords + (size_t)b * (MM * 3);
    float jx = cb[j * 3], jy = cb[j * 3 + 1], jz = cb[j * 3 + 2];
    v4f c0 = *(const v4f*)(cb + k0 * 3);
    v4f c1 = *(const v4f*)(cb + k0 * 3 + 4);
    v4f c2 = *(const v4f*)(cb + k0 * 3 + 8);
    float kc[12] = {c0.x, c0.y, c0.z, c0.w, c1.x, c1.y, c1.z, c1.w,
                    c2.x, c2.y, c2.z, c2.w};

    float d[4];
#pragma unroll
    for (int e = 0; e < 4; ++e) {
        float dx = kc[3 * e]     - jx;
        float dy = kc[3 * e + 1] - jy;
        float dz = kc[3 * e + 2] - jz;
        float dist = sqrtf(dx * dx + dy * dy + dz * dz);
        bool adj = ((k0 + e) != j) && (dist < CUTOFF_V);
        d[e] = adj ? dist : 0.0f;
    }
    v4f res = {d[0], d[1], d[2], d[3]};
    __builtin_nontemporal_store(res, (v4f*)(dists + (size_t)q * 4));
}

extern "C" void kernel_launch(void* const* d_in, const int* in_sizes, int n_in,
                              void* d_out, int out_size, void* d_ws, size_t ws_size,
                              hipStream_t stream) {
    const float* coords = (const float*)d_in[1];

    float* out    = (float*)d_out;
    float* dists  = out;                                // B*M*M
    float* angles = out + (size_t)BMOL * MM * MM;       // B*M*M*M

    dists_kernel<<<dim3(288), dim3(256), 0, stream>>>(coords, dists);
    angles_kernel<<<dim3(ANG_BLOCKS), dim3(256), 0, stream>>>(coords, angles);
}

// Round 6
// 35.502 us; speedup vs baseline: 1.1342x; 1.1342x over previous
//
#include <hip/hip_runtime.h>

#define MM 48
#define BMOL 128
#define CUTOFF_V 1.5f
#define PI_F 3.14159265358979f

typedef float v4f __attribute__((ext_vector_type(4)));

// acos via A&S 4.4.45 (max err 6.7e-5); equals atan2(sqrt(n2i*n2k - a*a), a)
// for x = a * rsqrt(n2i) * rsqrt(n2k). acos(+-1) gives 0 / pi, matching
// atan2(0, +-|a|).
__device__ __forceinline__ float acos_poly(float x) {
    x = fminf(fmaxf(x, -1.0f), 1.0f);
    float s = fabsf(x);
    float p = sqrtf(1.0f - s) *
              (1.5707288f + s * (-0.2121144f + s * (0.074261f - 0.0187293f * s)));
    return (x >= 0.0f) ? p : (PI_F - p);
}

// coords of atoms k0..k0+3 of one molecule: 12 consecutive floats, 48B-aligned.
__device__ __forceinline__ void load_kquad(const float* __restrict__ cb, int k0,
                                           float kx[4], float ky[4], float kz[4]) {
    v4f c0 = *(const v4f*)(cb + k0 * 3);
    v4f c1 = *(const v4f*)(cb + k0 * 3 + 4);
    v4f c2 = *(const v4f*)(cb + k0 * 3 + 8);
    kx[0] = c0.x; ky[0] = c0.y; kz[0] = c0.z;
    kx[1] = c0.w; ky[1] = c1.x; kz[1] = c1.y;
    kx[2] = c1.z; ky[2] = c1.w; kz[2] = c2.x;
    kx[3] = c2.y; ky[3] = c2.z; kz[3] = c2.w;
}

// Fused flat kernel over the whole output viewed as float4 quads:
//   quads [0, 73728)          = dists  [B,48,48]
//   quads [73728, 3612672)    = angles [B,48,48,48]
// Grid-stride, #pragma unroll 1 (R5 regressed from full-unroll register
// spills). Each wave keeps NITER independent nt stores in flight -> store
// bandwidth-bound, not store latency-bound (the R2-R4 limiter).
#define NBLK  2016
#define NITER 7   // 2016*256*7 = 3,612,672 quads, exact cover

__global__ __launch_bounds__(256)
void dimenet_fused_kernel(const float* __restrict__ coords,
                          float* __restrict__ out)
{
    const int tid = blockIdx.x * 256 + threadIdx.x;
    const int nthreads = NBLK * 256;

#pragma unroll 1
    for (int it = 0; it < NITER; ++it) {
        const int Q = tid + it * nthreads;
        v4f res;

        if (Q < 73728) {
            // ---- dists quad: Q = (b*48 + j)*12 + k0/4 ----
            int b   = Q / 576;
            int rem = Q - b * 576;
            int j   = rem / 12;
            int k0  = (rem - j * 12) * 4;

            const float* cb = coords + b * (MM * 3);
            float jx = cb[j * 3], jy = cb[j * 3 + 1], jz = cb[j * 3 + 2];
            float kx[4], ky[4], kz[4];
            load_kquad(cb, k0, kx, ky, kz);

            float d[4];
#pragma unroll
            for (int e = 0; e < 4; ++e) {
                float dx = kx[e] - jx, dy = ky[e] - jy, dz = kz[e] - jz;
                float dist = sqrtf(dx * dx + dy * dy + dz * dz);
                bool adj = ((k0 + e) != j) && (dist < CUTOFF_V);
                d[e] = adj ? dist : 0.0f;
            }
            res = (v4f){d[0], d[1], d[2], d[3]};
        } else {
            // ---- angles quad: qa = ((b*48 + j)*48 + i)*12 + k0/4 ----
            int qa  = Q - 73728;
            int q12 = qa / 12;
            int k0  = (qa - q12 * 12) * 4;
            int i   = q12 % 48;
            int t2  = q12 / 48;
            int j   = t2 % 48;
            int b   = t2 / 48;

            const float* cb = coords + b * (MM * 3);
            float jx = cb[j * 3], jy = cb[j * 3 + 1], jz = cb[j * 3 + 2];
            float ix = cb[i * 3], iy = cb[i * 3 + 1], iz = cb[i * 3 + 2];
            float kx[4], ky[4], kz[4];
            load_kquad(cb, k0, kx, ky, kz);

            float vix = ix - jx, viy = iy - jy, viz = iz - jz;
            float n2i = vix * vix + viy * viy + viz * viz;
            bool adji = (i != j) && (sqrtf(n2i) < CUTOFF_V);
            float wi  = adji ? rsqrtf(n2i) : 0.0f;

            float ang[4];
#pragma unroll
            for (int e = 0; e < 4; ++e) {
                float vkx = kx[e] - jx, vky = ky[e] - jy, vkz = kz[e] - jz;
                float n2k = vkx * vkx + vky * vky + vkz * vkz;
                int   k   = k0 + e;
                bool adjk = (k != j) && (sqrtf(n2k) < CUTOFF_V);
                float wk  = adjk ? rsqrtf(n2k) : 0.0f;
                float a   = vix * vkx + viy * vky + viz * vkz;
                float w   = wi * wk;               // >0 iff both edges adjacent
                float r   = acos_poly(a * w);
                bool mask = (w > 0.0f) && (i != k);
                ang[e] = mask ? r : 0.0f;
            }
            res = (v4f){ang[0], ang[1], ang[2], ang[3]};
        }

        __builtin_nontemporal_store(res, (v4f*)out + Q);
    }
}

extern "C" void kernel_launch(void* const* d_in, const int* in_sizes, int n_in,
                              void* d_out, int out_size, void* d_ws, size_t ws_size,
                              hipStream_t stream) {
    // inputs: atomic_ns [N] int, coords [N,3] f32, batch_node_vec [N] i64.
    // Only coords matters (molecules are contiguous 48-atom blocks).
    const float* coords = (const float*)d_in[1];
    float* out = (float*)d_out;   // dists [B*48*48] then angles [B*48*48*48]

    dimenet_fused_kernel<<<dim3(NBLK), dim3(256), 0, stream>>>(coords, out);
}

// Round 7
// 30.094 us; speedup vs baseline: 1.3380x; 1.1797x over previous
//
#include <hip/hip_runtime.h>

#define MM 48
#define BMOL 128
#define CUTOFF_V 1.5f
#define PI_F 3.14159265358979f

typedef float v4f __attribute__((ext_vector_type(4)));

// acos via A&S 4.4.45 (max err 6.7e-5); equals atan2(sqrt(n2i*n2k - a*a), a)
// for x = a * rsqrt(n2i) * rsqrt(n2k).
__device__ __forceinline__ float acos_poly(float x) {
    x = fminf(fmaxf(x, -1.0f), 1.0f);
    float s = fabsf(x);
    float p = sqrtf(1.0f - s) *
              (1.5707288f + s * (-0.2121144f + s * (0.074261f - 0.0187293f * s)));
    return (x >= 0.0f) ? p : (PI_F - p);
}

// ---------------- Kernel A: pair table + dists ----------------
// One thread per 4 pairs (b, j, k0..k0+3).  73,728 threads = 288 x 256.
// table[(b*48+j)*48 + k] = {vx, vy, vz, w} with v = r_k - r_j,
// w = adj ? rsqrt(d2) : 0 (adjacency EXACTLY as reference: sqrtf(d2) < 1.5).
// dists[b][j][k] = adj ? dist : 0.
__global__ __launch_bounds__(256)
void pair_table_kernel(const float* __restrict__ coords,
                       float* __restrict__ dists,
                       v4f* __restrict__ table)
{
    const int q  = blockIdx.x * 256 + threadIdx.x;   // 0..73727
    const int b   = q / 576;
    const int rem = q - b * 576;
    const int j   = rem / 12;
    const int k0  = (rem - j * 12) * 4;

    const float* cb = coords + b * (MM * 3);
    const float jx = cb[j * 3], jy = cb[j * 3 + 1], jz = cb[j * 3 + 2];
    v4f c0 = *(const v4f*)(cb + k0 * 3);
    v4f c1 = *(const v4f*)(cb + k0 * 3 + 4);
    v4f c2 = *(const v4f*)(cb + k0 * 3 + 8);
    const float kc[12] = {c0.x, c0.y, c0.z, c0.w, c1.x, c1.y, c1.z, c1.w,
                          c2.x, c2.y, c2.z, c2.w};

    float d[4];
#pragma unroll
    for (int e = 0; e < 4; ++e) {
        float dx = kc[3 * e] - jx, dy = kc[3 * e + 1] - jy, dz = kc[3 * e + 2] - jz;
        float d2 = dx * dx + dy * dy + dz * dz;
        float dist = sqrtf(d2);
        bool adj = ((k0 + e) != j) && (dist < CUTOFF_V);
        float w = adj ? rsqrtf(d2) : 0.0f;
        d[e] = adj ? dist : 0.0f;
        table[(size_t)q * 4 + e] = (v4f){dx, dy, dz, w};   // normal store: L2-resident for kernel B
    }
    v4f res = {d[0], d[1], d[2], d[3]};
    __builtin_nontemporal_store(res, (v4f*)dists + q);
}

// ---------------- Kernel B: angles from the table ----------------
// Flat over 3,538,944 angle quads. Per quad: 5 contiguous dwordx4 loads
// (pair_i + 4 pair_k, all inside one 768B row -> L1-hot), ~60 VALU,
// one 16B nt store. 8 independent iters per thread.
#define NBLK  1728
#define NITER 8   // 1728*256*8 = 3,538,944 quads, exact cover

__global__ __launch_bounds__(256)
void angles_kernel(const v4f* __restrict__ table,
                   float* __restrict__ angles)
{
    const int tid = blockIdx.x * 256 + threadIdx.x;
    const int nth = NBLK * 256;

#pragma unroll 2
    for (int it = 0; it < NITER; ++it) {
        const int qa = tid + it * nth;
        const int q12 = qa / 12;
        const int k0  = (qa - q12 * 12) * 4;
        const int t2  = q12 / 48;            // b*48 + j
        const int i   = q12 - t2 * 48;
        const int row = t2 * 48;             // table row base for (b,j)

        const v4f pi = table[row + i];
        const v4f p0 = table[row + k0];
        const v4f p1 = table[row + k0 + 1];
        const v4f p2 = table[row + k0 + 2];
        const v4f p3 = table[row + k0 + 3];
        const float wi = pi.w;

        float ang[4];
        const v4f pk[4] = {p0, p1, p2, p3};
#pragma unroll
        for (int e = 0; e < 4; ++e) {
            float a  = pi.x * pk[e].x + pi.y * pk[e].y + pi.z * pk[e].z;
            float wp = wi * pk[e].w;            // >0 iff both edges adjacent
            float r  = acos_poly(a * wp);
            bool mask = (wp > 0.0f) && (i != k0 + e);
            ang[e] = mask ? r : 0.0f;
        }

        v4f res = {ang[0], ang[1], ang[2], ang[3]};
        __builtin_nontemporal_store(res, (v4f*)angles + qa);
    }
}

extern "C" void kernel_launch(void* const* d_in, const int* in_sizes, int n_in,
                              void* d_out, int out_size, void* d_ws, size_t ws_size,
                              hipStream_t stream) {
    // inputs: atomic_ns [N] int, coords [N,3] f32, batch_node_vec [N] i64.
    // Only coords matters (molecules are contiguous 48-atom blocks).
    const float* coords = (const float*)d_in[1];

    float* out    = (float*)d_out;
    float* dists  = out;                                // B*48*48
    float* angles = out + (size_t)BMOL * MM * MM;       // B*48*48*48
    v4f*   table  = (v4f*)d_ws;                         // 294,912 float4 = 4.7 MB

    pair_table_kernel<<<dim3(288), dim3(256), 0, stream>>>(coords, dists, table);
    angles_kernel<<<dim3(NBLK), dim3(256), 0, stream>>>(table, angles);
}

// Round 8
// 21.337 us; speedup vs baseline: 1.8871x; 1.4104x over previous
//
#include <hip/hip_runtime.h>

#define MM 48
#define BMOL 128
#define CUTOFF_V 1.5f
#define PI_F 3.14159265358979f

typedef float v4f __attribute__((ext_vector_type(4)));

// acos via A&S 4.4.45 (max err 6.7e-5); equals atan2(sqrt(n2i*n2k - a*a), a)
// for x = a * rsqrt(n2i) * rsqrt(n2k).
__device__ __forceinline__ float acos_poly(float x) {
    x = fminf(fmaxf(x, -1.0f), 1.0f);
    float s = fabsf(x);
    float p = sqrtf(1.0f - s) *
              (1.5707288f + s * (-0.2121144f + s * (0.074261f - 0.0187293f * s)));
    return (x >= 0.0f) ? p : (PI_F - p);
}

// ONE WAVE per (b, j) slice. 6144 blocks x 64 threads, all co-resident
// (24 one-wave blocks/CU): no multi-wave barrier, no sequential block
// generations, 9 independent 1KB nt stores in flight per wave.
//
// LDS layouts tuned for bank-conflict-free reads (32 banks x 4B):
//  - paos: AoS {vx,vy,vz,w}, entry k at word 8k (32B stride) -> pi is ONE
//    broadcast ds_read_b128.
//  - s?p : SoA per component, k-quad g at word 20g (80B stride, 16B aligned)
//    -> the 12 distinct quad addresses land on banks {0,20,8,28,16,4,24,12,...}
//    = 2-way max (free), instead of the 6-way conflict of the natural layout.
__global__ __launch_bounds__(64, 6)
void slice_kernel(const float* __restrict__ coords,
                  float* __restrict__ dists,
                  float* __restrict__ angles)
{
    const int bj = blockIdx.x;
    const int b  = bj / MM;
    const int j  = bj - b * MM;

    __shared__ __align__(16) float paos[MM * 8];                   // 1536 B
    __shared__ __align__(16) float sxp[240];                       // 960 B
    __shared__ __align__(16) float syp[240];
    __shared__ __align__(16) float szp[240];
    __shared__ __align__(16) float swp[240];

    const int t = threadIdx.x;

    if (t < MM) {
        const float* cb = coords + b * (MM * 3);
        const float jx = cb[j * 3], jy = cb[j * 3 + 1], jz = cb[j * 3 + 2];
        float dx = cb[t * 3]     - jx;
        float dy = cb[t * 3 + 1] - jy;
        float dz = cb[t * 3 + 2] - jz;
        float d2 = dx * dx + dy * dy + dz * dz;
        float dist = sqrtf(d2);
        bool adj = (t != j) && (dist < CUTOFF_V);     // exact reference semantics
        float w  = adj ? rsqrtf(d2) : 0.0f;
        *(v4f*)&paos[t * 8] = (v4f){dx, dy, dz, w};
        int widx = 20 * (t >> 2) + (t & 3);
        sxp[widx] = dx; syp[widx] = dy; szp[widx] = dz; swp[widx] = w;
        __builtin_nontemporal_store(adj ? dist : 0.0f,
                                    dists + (size_t)bj * MM + t);
    }
    __syncthreads();   // single-wave WG: compiles to waitcnt + trivial barrier

    float* ang_base = angles + (size_t)bj * (MM * MM);

#pragma unroll 3
    for (int it = 0; it < 9; ++it) {
        const int q = t + it * 64;       // 0..575 quad of this 48x48 slice
        const int i = q / 12;
        const int m = q - i * 12;        // k-quad index, k0 = 4m
        const int k0 = m * 4;

        v4f pi = *(const v4f*)&paos[i * 8];
        v4f xk = *(const v4f*)&sxp[m * 20];
        v4f yk = *(const v4f*)&syp[m * 20];
        v4f zk = *(const v4f*)&szp[m * 20];
        v4f wk = *(const v4f*)&swp[m * 20];

        float ang[4];
#pragma unroll
        for (int e = 0; e < 4; ++e) {
            float a  = pi.x * xk[e] + pi.y * yk[e] + pi.z * zk[e];
            float wp = pi.w * wk[e];            // >0 iff both edges adjacent
            float r  = acos_poly(a * wp);
            bool mask = (wp > 0.0f) && (i != k0 + e);
            ang[e] = mask ? r : 0.0f;
        }

        __builtin_nontemporal_store((v4f){ang[0], ang[1], ang[2], ang[3]},
                                    (v4f*)(ang_base + q * 4));
    }
}

extern "C" void kernel_launch(void* const* d_in, const int* in_sizes, int n_in,
                              void* d_out, int out_size, void* d_ws, size_t ws_size,
                              hipStream_t stream) {
    // inputs: atomic_ns [N] int, coords [N,3] f32, batch_node_vec [N] i64.
    // Only coords matters (molecules are contiguous 48-atom blocks).
    const float* coords = (const float*)d_in[1];

    float* out    = (float*)d_out;
    float* dists  = out;                                // B*48*48
    float* angles = out + (size_t)BMOL * MM * MM;       // B*48*48*48

    slice_kernel<<<dim3(BMOL * MM), dim3(64), 0, stream>>>(coords, dists, angles);
}